// Round 7
// baseline (281.527 us; speedup 1.0000x reference)
//
#include <hip/hip_runtime.h>
#include <math.h>

#define HDIM  1024
#define MDIM  2048
#define RSQRT_D 0.08838834764831844f   // 1/sqrt(128)

// ---- workspace layout (float offsets) ----
// Only w needs zeroing (kw atomics); kq zeroes it. Barrier counters zeroed by kab.
#define OFF_W     0          // w[8][2048]      (kw, atomic accum; zeroed by kq)
#define OFF_BETA  16384      // beta[8]         (kw block 256, non-atomic)
#define OFF_Z     16392      // Z[8]            (kyfo block 0, non-atomic)
#define OFF_Q     16400      // q[1024]         (kq)
#define OFF_FEAT  17424      // feat[1024]      (kyfo phase F)
#define OFF_Y     18448      // y[8][2048]      (kyfo phase Y)
#define OFF_ZP    34832      // zpart[512][8]   (kab)
#define OFF_BAR   38928      // 2 uints: kyfo barrier counters (zeroed by kab)
#define OFF_YBUF  301072     // ybuf[512][8][2048] (kab, 33.6 MB) -> end 34.8 MB

__device__ __forceinline__ float dot4(float4 a, float4 b) {
  return a.x * b.x + a.y * b.y + a.z * b.z + a.w * b.w;
}
__device__ __forceinline__ void fma4(float4& acc, float s, float4 v) {
  acc.x = fmaf(s, v.x, acc.x); acc.y = fmaf(s, v.y, acc.y);
  acc.z = fmaf(s, v.z, acc.z); acc.w = fmaf(s, v.w, acc.w);
}
__device__ __forceinline__ void add4(float4& a, float4 v) {
  a.x += v.x; a.y += v.y; a.z += v.z; a.w += v.w;
}

// ---- inline grid barrier for a 256-block plain-launched kernel.
// Hang-proof: all 256 blocks increment BEFORE spinning, so the grid itself
// always reaches the target; a poisoned (nonzero) start can only release
// early (harmless outside the properly-sequenced flow), never deadlock.
__device__ __forceinline__ void kbar(unsigned* ctr, int tid) {
  __syncthreads();                 // drain this block's stores
  if (tid == 0) {
    __hip_atomic_fetch_add(ctr, 1u, __ATOMIC_ACQ_REL, __HIP_MEMORY_SCOPE_AGENT);
    while (__hip_atomic_load(ctr, __ATOMIC_RELAXED, __HIP_MEMORY_SCOPE_AGENT) < 256u)
      __builtin_amdgcn_s_sleep(8);
    (void)__hip_atomic_load(ctr, __ATOMIC_ACQUIRE, __HIP_MEMORY_SCOPE_AGENT);
  }
  __syncthreads();
}

// ---- kq: q[j] = x.Wq[j,:] + bq[j] (wave per j); also zeroes w for kw's atomics ----
__global__ __launch_bounds__(256) void kq(const float* __restrict__ x,
                                          const float* __restrict__ Wq,
                                          const float* __restrict__ bq,
                                          float* __restrict__ ws) {
  int tid = threadIdx.x, lane = tid & 63;
  int j = blockIdx.x * 4 + (tid >> 6);
  const float4* xr = (const float4*)x;
  const float4* wr = (const float4*)(Wq + (size_t)j * HDIM);
  float acc = 0.f;
#pragma unroll
  for (int i = 0; i < 4; ++i) {
    int idx = i * 64 + lane;
    acc += dot4(xr[idx], wr[idx]);
  }
#pragma unroll
  for (int off = 32; off; off >>= 1) acc += __shfl_xor(acc, off);
  if (lane == 0) ws[OFF_Q + j] = acc + bq[j];
  // zero w slice: 16384 floats / 256 blocks = 64 per block
  if (tid < 64) ws[OFF_W + blockIdx.x * 64 + tid] = 0.f;
}

// ---- kw: w[n][m] += q[c]*Wk[c][m] (c-chunked atomics, grid 256);
//          block 256: beta[n] = sum_{c%8==n} q[c]*bk[c] (non-atomic) ----
__global__ __launch_bounds__(256) void kw(const float* __restrict__ Wk,
                                          const float* __restrict__ bk,
                                          float* __restrict__ ws) {
  __shared__ float lds[32];
  int tid = threadIdx.x;
  const float* q = ws + OFF_Q;
  if (blockIdx.x == 256) {   // beta block
    float b = 0.f;
#pragma unroll
    for (int i = 0; i < 4; ++i) {
      int c = tid + 256 * i;
      b = fmaf(q[c], bk[c], b);
    }
    b += __shfl_xor(b, 8); b += __shfl_xor(b, 16); b += __shfl_xor(b, 32);
    if ((tid & 63) < 8) lds[(tid >> 6) * 8 + (tid & 7)] = b;
    __syncthreads();
    if (tid < 8)
      ws[OFF_BETA + tid] = lds[tid] + lds[8 + tid] + lds[16 + tid] + lds[24 + tid];
    return;
  }
  int mc = blockIdx.x & 7, cc = blockIdx.x >> 3;   // 8 m-chunks x 32 c-chunks
  int m = mc * 256 + tid;
  float acc[8];
#pragma unroll
  for (int n = 0; n < 8; ++n) acc[n] = 0.f;
  int c0 = cc * 32;
#pragma unroll
  for (int cb = 0; cb < 32; cb += 8) {
#pragma unroll
    for (int u = 0; u < 8; ++u)
      acc[u] = fmaf(q[c0 + cb + u], Wk[(size_t)(c0 + cb + u) * MDIM + m], acc[u]);
  }
#pragma unroll
  for (int n = 0; n < 8; ++n) atomicAdd(&ws[OFF_W + n * MDIM + m], acc[n]);
}

// ---- kab: fused scores + softmax + weighted-sum (R6-proven body).
// Grid 512 x 512 threads, LB(512,4) -> 2 blocks/CU. Block owns 32 rows x 2048 cols.
// Also zeroes kyfo's barrier counters (block 0, before kyfo runs on the stream).
__global__ __launch_bounds__(512, 4) void kab(const float* __restrict__ mem,
                                              float* __restrict__ ws) {
  __shared__ float4 wlds[4096];            // w[8][2048] staged, 64 KB
  __shared__ __align__(16) float pp[256];  // p[32 rows][8 heads]
  __shared__ float zz[64];
  __shared__ float bb[8];
  int tid = threadIdx.x, lane = tid & 63, wv = tid >> 6;
  int bid = blockIdx.x;
  int r0 = bid * 32;

  if (bid == 0 && tid < 2) ((unsigned*)(ws + OFF_BAR))[tid] = 0u;

  const float4* wsrc = (const float4*)(ws + OFF_W);
#pragma unroll
  for (int k = 0; k < 8; ++k)
    wlds[k * 512 + tid] = wsrc[k * 512 + tid];
  if (tid < 8) bb[tid] = ws[OFF_BETA + tid];

  const float* rowp = mem + (size_t)(r0 + wv * 4) * MDIM;
  float4 mva[4], mvan[4], mvb[4];
#pragma unroll
  for (int i = 0; i < 4; ++i)
    mva[i] = *(const float4*)(rowp + (i * 64 + lane) * 4);
  __syncthreads();

  float zacc[8];
#pragma unroll
  for (int n = 0; n < 8; ++n) zacc[n] = 0.f;

#pragma unroll
  for (int rl = 0; rl < 4; ++rl) {
    // chunk1 (cols 1024..2047) of current row: issue early
#pragma unroll
    for (int i = 0; i < 4; ++i)
      mvb[i] = *(const float4*)(rowp + 1024 + (i * 64 + lane) * 4);
    float acc[8];
#pragma unroll
    for (int n = 0; n < 8; ++n) acc[n] = 0.f;
#pragma unroll
    for (int pass = 0; pass < 4; ++pass) {
      int cq = pass * 64 + lane;
#pragma unroll
      for (int n = 0; n < 8; ++n) {
        float4 w4 = wlds[n * 512 + cq];
        acc[n] = fmaf(mva[pass].x, w4.x, acc[n]);
        acc[n] = fmaf(mva[pass].y, w4.y, acc[n]);
        acc[n] = fmaf(mva[pass].z, w4.z, acc[n]);
        acc[n] = fmaf(mva[pass].w, w4.w, acc[n]);
      }
    }
    if (rl < 3) {   // prefetch next row's chunk0 under chunk1 compute + butterfly
#pragma unroll
      for (int i = 0; i < 4; ++i)
        mvan[i] = *(const float4*)(rowp + MDIM + (i * 64 + lane) * 4);
    }
#pragma unroll
    for (int pass = 0; pass < 4; ++pass) {
      int cq = 256 + pass * 64 + lane;
#pragma unroll
      for (int n = 0; n < 8; ++n) {
        float4 w4 = wlds[n * 512 + cq];
        acc[n] = fmaf(mvb[pass].x, w4.x, acc[n]);
        acc[n] = fmaf(mvb[pass].y, w4.y, acc[n]);
        acc[n] = fmaf(mvb[pass].z, w4.z, acc[n]);
        acc[n] = fmaf(mvb[pass].w, w4.w, acc[n]);
      }
    }
#pragma unroll
    for (int off = 1; off < 64; off <<= 1)
#pragma unroll
      for (int n = 0; n < 8; ++n)
        acc[n] += __shfl_xor(acc[n], off);
#pragma unroll
    for (int n = 0; n < 8; ++n) {
      float p = __expf((acc[n] + bb[n]) * RSQRT_D);
      zacc[n] += p;
      if (lane == 0) pp[(wv * 4 + rl) * 8 + n] = p;
    }
#pragma unroll
    for (int i = 0; i < 4; ++i) mva[i] = mvan[i];
    rowp += MDIM;
  }
  if (lane == 0) {
#pragma unroll
    for (int n = 0; n < 8; ++n) zz[wv * 8 + n] = zacc[n];
  }
  __syncthreads();
  if (tid < 8) {
    float z = 0.f;
#pragma unroll
    for (int w = 0; w < 8; ++w) z += zz[w * 8 + tid];
    ws[OFF_ZP + bid * 8 + tid] = z;
  }

  // ---- phase B: y += p * mem for the same 32 rows (L3-hot re-read) ----
  float4 acc4[8];
#pragma unroll
  for (int n = 0; n < 8; ++n) acc4[n] = make_float4(0.f, 0.f, 0.f, 0.f);
  const float* base = mem + (size_t)r0 * MDIM + tid * 4;
  const float4* pp4 = (const float4*)pp;
#pragma unroll 4
  for (int r = 0; r < 32; ++r) {
    float4 mv = *(const float4*)(base + (size_t)r * MDIM);
    float4 pA = pp4[r * 2], pB = pp4[r * 2 + 1];   // broadcast
    fma4(acc4[0], pA.x, mv); fma4(acc4[1], pA.y, mv);
    fma4(acc4[2], pA.z, mv); fma4(acc4[3], pA.w, mv);
    fma4(acc4[4], pB.x, mv); fma4(acc4[5], pB.y, mv);
    fma4(acc4[6], pB.z, mv); fma4(acc4[7], pB.w, mv);
  }
  float* yb = ws + OFF_YBUF + (size_t)bid * 16384 + tid * 4;
#pragma unroll
  for (int n = 0; n < 8; ++n)
    *(float4*)(yb + n * MDIM) = acc4[n];
}

// ---- kyfo: fused tail. Grid 256 (1 block/CU -> all co-resident).
// Phase Y: y = sum_b ybuf[b] (k4c body) + block0 Z-reduce; barrier;
// Phase F: feat (kf body); barrier; Phase O: out (ko body). ----
__global__ __launch_bounds__(256) void kyfo(const float* __restrict__ x,
                                            const float* __restrict__ Wv,
                                            const float* __restrict__ bv,
                                            const float* __restrict__ Wo,
                                            const float* __restrict__ bo,
                                            float* __restrict__ ws,
                                            float* __restrict__ out) {
  __shared__ __align__(16) float lds[1056];
  int tid = threadIdx.x, lane = tid & 63, wv = tid >> 6;
  int bid = blockIdx.x;

  // ---- phase Y: y[quad] = sum_{b<512} ybuf[b][quad]  (16 quads/block) ----
  {
    float4* sA = (float4*)lds;      // 256 float4
    int quad = bid * 16 + (tid & 15);
    int b0 = (tid >> 4) * 32;
    const float4* src = (const float4*)(ws + OFF_YBUF);
    float4 acc = make_float4(0.f, 0.f, 0.f, 0.f);
    for (int b = b0; b < b0 + 32; ++b)
      add4(acc, src[(size_t)b * 4096 + quad]);
    sA[(tid & 15) * 16 + (tid >> 4)] = acc;
    __syncthreads();
    if (tid < 16) {
      float4 s = sA[tid * 16];
#pragma unroll
      for (int j = 1; j < 16; ++j) add4(s, sA[tid * 16 + j]);
      ((float4*)(ws + OFF_Y))[bid * 16 + tid] = s;
    }
  }
  if (bid == 0) {   // Z[n] = sum_b zpart[b][n]
    int n = tid & 7;
    float z = 0.f;
#pragma unroll
    for (int i = 0; i < 16; ++i)
      z += ws[OFF_ZP + ((tid >> 3) + 32 * i) * 8 + n];
    z += __shfl_xor(z, 8); z += __shfl_xor(z, 16); z += __shfl_xor(z, 32);
    float* zzz = lds + 1024;
    if (lane < 8) zzz[wv * 8 + lane] = z;
    __syncthreads();
    if (tid < 8)
      ws[OFF_Z + tid] = zzz[tid] + zzz[8 + tid] + zzz[16 + tid] + zzz[24 + tid];
  }
  kbar((unsigned*)(ws + OFF_BAR), tid);

  // ---- phase F: feat[c] = (y[c&7] . Wv[c,:]) / Z[c&7] + bv[c] (wave per c) ----
  {
    int c = bid * 4 + wv;
    int n = c & 7;
    const float4* yb = (const float4*)(ws + OFF_Y + n * MDIM);
    const float4* wb = (const float4*)(Wv + (size_t)c * MDIM);
    float acc = 0.f;
#pragma unroll
    for (int s = 0; s < 8; ++s) {
      int idx = s * 64 + lane;
      acc += dot4(yb[idx], wb[idx]);
    }
#pragma unroll
    for (int off = 32; off; off >>= 1) acc += __shfl_xor(acc, off);
    if (lane == 0) ws[OFF_FEAT + c] = acc / ws[OFF_Z + n] + bv[c];
  }
  kbar((unsigned*)(ws + OFF_BAR) + 1, tid);

  // ---- phase O: out[j] = relu(x.Wo[j,:1024] + feat.Wo[j,1024:] + bo[j]) ----
  {
    int j = bid * 4 + wv;
    const float4* wb = (const float4*)(Wo + (size_t)j * 2048);
    const float4* xr = (const float4*)x;
    const float4* fr = (const float4*)(ws + OFF_FEAT);
    float acc = 0.f;
#pragma unroll
    for (int s = 0; s < 4; ++s) {
      int idx = s * 64 + lane;
      acc += dot4(xr[idx], wb[idx]);
      acc += dot4(fr[idx], wb[256 + idx]);
    }
#pragma unroll
    for (int off = 32; off; off >>= 1) acc += __shfl_xor(acc, off);
    if (lane == 0) out[j] = fmaxf(acc + bo[j], 0.f);
  }
}

extern "C" void kernel_launch(void* const* d_in, const int* in_sizes, int n_in,
                              void* d_out, int out_size, void* d_ws, size_t ws_size,
                              hipStream_t stream) {
  const float* x   = (const float*)d_in[0];
  const float* mem = (const float*)d_in[1];
  const float* Wq  = (const float*)d_in[2];
  const float* bq  = (const float*)d_in[3];
  const float* Wk  = (const float*)d_in[4];
  const float* bk  = (const float*)d_in[5];
  const float* Wv  = (const float*)d_in[6];
  const float* bv  = (const float*)d_in[7];
  const float* Wo  = (const float*)d_in[8];
  const float* bo  = (const float*)d_in[9];
  float* ws  = (float*)d_ws;
  float* out = (float*)d_out;

  kq  <<<256, 256, 0, stream>>>(x, Wq, bq, ws);
  kw  <<<257, 256, 0, stream>>>(Wk, bk, ws);
  kab <<<512, 512, 0, stream>>>(mem, ws);
  kyfo<<<256, 256, 0, stream>>>(x, Wv, bv, Wo, bo, ws, out);
}